// Round 19
// baseline (70.950 us; speedup 1.0000x reference)
//
#include <hip/hip_runtime.h>
#include <hip/hip_bf16.h>

#define BATCH  512
#define IN_F   4096
#define OUT_F  4096
#define CAP    208     // bucket capacity; Poisson(122), overflow prob ~1e-11/row
#define CSTR   16      // counts stride (ints): 1 counter per 64-B line (atomic contention fix)

typedef __attribute__((ext_vector_type(8))) short bf16x8;   // 8 bf16 = 4 VGPR (MFMA A/B frag)
typedef __attribute__((ext_vector_type(4))) float f32x4;    // MFMA C/D frag

// bf16 round-to-nearest-even bits from fp32
__device__ __forceinline__ unsigned bf16_bits(float f) {
    unsigned u = __float_as_uint(f);
    return (u + 0x7FFFu + ((u >> 16) & 1u)) >> 16;
}
__device__ __forceinline__ float bf16_val(unsigned bits16) {
    return __uint_as_float(bits16 << 16);
}

// ---------------- 0) convert x fp32 -> bf16  +  zero counts (R14-exact) ----------------
__global__ void convert_cnt_kernel(const float* __restrict__ x, __hip_bfloat16* __restrict__ xb,
                                   int* __restrict__ counts) {
    const int NC = BATCH * IN_F / 4;      // x convert threads (float4 each)
    int i = blockIdx.x * blockDim.x + threadIdx.x;
    if (i < NC) {
        float4 v = ((const float4*)x)[i];
        unsigned lo = bf16_bits(v.x) | (bf16_bits(v.y) << 16);
        unsigned hi = bf16_bits(v.z) | (bf16_bits(v.w) << 16);
        ((uint2*)xb)[i] = make_uint2(lo, hi);
    } else if (i < NC + OUT_F) {
        counts[(i - NC) * CSTR] = 0;                      // one counter per line
    }
}

// ---------------- 1) scatter entries into fixed-capacity row buckets (R14-exact) ----------------
__global__ void scatter_pairs_kernel(const int* __restrict__ rows,
                                     const int* __restrict__ cols,
                                     const float* __restrict__ w,
                                     int nnz,
                                     int* __restrict__ counts,
                                     unsigned* __restrict__ pairs) {
    int i = blockIdx.x * blockDim.x + threadIdx.x;
    int i4 = i * 4;
    if (i4 + 4 <= nnz) {
        int4   r  = ((const int4*)rows)[i];
        int4   c  = ((const int4*)cols)[i];
        float4 wv = ((const float4*)w)[i];
        int p0 = atomicAdd(&counts[r.x * CSTR], 1);
        if (p0 < CAP) pairs[(size_t)r.x * CAP + p0] = (bf16_bits(wv.x) << 16) | (unsigned)c.x;
        int p1 = atomicAdd(&counts[r.y * CSTR], 1);
        if (p1 < CAP) pairs[(size_t)r.y * CAP + p1] = (bf16_bits(wv.y) << 16) | (unsigned)c.y;
        int p2 = atomicAdd(&counts[r.z * CSTR], 1);
        if (p2 < CAP) pairs[(size_t)r.z * CAP + p2] = (bf16_bits(wv.z) << 16) | (unsigned)c.z;
        int p3 = atomicAdd(&counts[r.w * CSTR], 1);
        if (p3 < CAP) pairs[(size_t)r.w * CAP + p3] = (bf16_bits(wv.w) << 16) | (unsigned)c.w;
    } else {
        for (int j = i4; j < nnz; ++j) {
            int rr = rows[j];
            int pp = atomicAdd(&counts[rr * CSTR], 1);
            if (pp < CAP) pairs[(size_t)rr * CAP + pp] = (bf16_bits(w[j]) << 16) | (unsigned)cols[j];
        }
    }
}

// ---------------- 2) densify: one block per output row -> bf16 dense W (R14-exact) ----------------
__global__ __launch_bounds__(256) void densify_rows_kernel(const unsigned* __restrict__ pairs,
                                                           const int* __restrict__ counts,
                                                           __hip_bfloat16* __restrict__ Wb) {
    __shared__ __align__(16) float row[IN_F];   // 16 KB
    const int r = blockIdx.x;
    const int t = threadIdx.x;
    const float4 z = make_float4(0.f, 0.f, 0.f, 0.f);
#pragma unroll
    for (int k = 0; k < IN_F / 4 / 256; ++k)
        ((float4*)row)[t + k * 256] = z;
    __syncthreads();
    int cnt = counts[r * CSTR];
    if (cnt > CAP) cnt = CAP;
    const unsigned* bucket = pairs + (size_t)r * CAP;
    for (int j = t; j < cnt; j += 256) {
        unsigned p = bucket[j];
        atomicAdd(&row[p & 0xFFFu], __uint_as_float(p & 0xFFFF0000u));
    }
    __syncthreads();
    unsigned* dst = (unsigned*)(Wb + (size_t)r * IN_F);
#pragma unroll
    for (int k = 0; k < (IN_F / 2) / 256; ++k) {
        int ui = t + k * 256;
        unsigned lo = bf16_bits(row[ui * 2]);
        unsigned hi = bf16_bits(row[ui * 2 + 1]);
        dst[ui] = lo | (hi << 16);
    }
}

// ---------------- 3) GEMM: 4 double-barrier phases/K-tile + counted vmcnt gate ----------------
// Geometry/mapping/epilogue = R14. NEW (m201-template port): LDS as [dbuf][half] half-
// tiles; each phase {quadrant ds_reads || half-tile stages for kt+2 || s_barrier ||
// setprio 16 MFMA || s_barrier}; ONE vmcnt(8) gate per K-tile at phase 3 (kt+2's 8
// loads stay airborne across barriers; drain-0 only at the tail). WAR safety: B-halves
// last ds_read in phase 1 -> restage phase 2; A-halves last read phase 2 -> restage
// phase 3; each restage is issued after the end-barrier of its last-reader phase.
#define BM  256
#define BN  256
#define BKT 64
#define KSPLIT 8
#define KH   (IN_F / KSPLIT)            // 512
#define NKTH (KH / BKT)                 // 8
#define NWG  ((BATCH / BM) * (OUT_F / BN) * KSPLIT)   // 256

__global__ __launch_bounds__(512, 1) void gemm_part_kernel(
    const __hip_bfloat16* __restrict__ xb,   // (512, 4096) row-major
    const __hip_bfloat16* __restrict__ Wb,   // (4096, 4096) = (N, K) row-major
    unsigned* __restrict__ parts) {          // KSPLIT x (256, 4096) uint (2 bf16 rows each)

    __shared__ __align__(16) __hip_bfloat16 As[2][2][128][BKT];   // [dbuf][half] 64 KB
    __shared__ __align__(16) __hip_bfloat16 Bs[2][2][128][BKT];   // 64 KB

    // XCD-paired decomposition (xcd heuristic: bid % 8)
    const int xcd = blockIdx.x & 7;
    const int r   = blockIdx.x >> 3;          // 0..31
    const int bn0 = (2 * xcd + (r & 1)) * BN; // n tile 0..15
    const int bm0 = ((r >> 1) & 1) * BM;      // m tile 0..1
    const int ksp = r >> 2;                   // 0..7
    const size_t k0 = (size_t)ksp * KH;

    const int t  = threadIdx.x;               // 0..511
    const int l  = t & 63;
    const int w  = t >> 6;                    // wave 0..7
    const int wr = w >> 2;                    // M-half 0..1 (owns A-half wr)
    const int wc = w & 3;                     // N-quarter 0..3 (owns B-half wc>>1)
    const int lr = l & 15;                    // frag lane
    const int lg = l >> 4;                    // k-group 0..3

    f32x4 acc[8][4] = {};

    // half-tile stage: 2 gload_lds/thread. chunk q: local row rl=q>>3 (0..127), slot
    // s=q&7 holds global k-chunk s^(rl&7) (pre-swizzled source, linear LDS dest).
#define STG_A(kt, hm) do {                                                                        \
    _Pragma("unroll")                                                                             \
    for (int j = 0; j < 2; ++j) {                                                                 \
        int q = t + j * 512; int rl = q >> 3; int kcg = (q & 7) ^ (rl & 7);                       \
        __builtin_amdgcn_global_load_lds(                                                         \
            (const unsigned*)(xb + (size_t)(bm0 + (hm) * 128 + rl) * IN_F + k0 + (kt) * BKT + kcg * 8), \
            (unsigned*)((__hip_bfloat16*)As[(kt) & 1][hm] + q * 8), 16, 0, 0);                    \
    }                                                                                             \
} while (0)
#define STG_B(kt, hn) do {                                                                        \
    _Pragma("unroll")                                                                             \
    for (int j = 0; j < 2; ++j) {                                                                 \
        int q = t + j * 512; int rl = q >> 3; int kcg = (q & 7) ^ (rl & 7);                       \
        __builtin_amdgcn_global_load_lds(                                                         \
            (const unsigned*)(Wb + (size_t)(bn0 + (hn) * 128 + rl) * IN_F + k0 + (kt) * BKT + kcg * 8), \
            (unsigned*)((__hip_bfloat16*)Bs[(kt) & 1][hn] + q * 8), 16, 0, 0);                    \
    }                                                                                             \
} while (0)

    const int xA = lr & 7;                    // (local row)&7 == lr&7 for all frags
    const int xB = lr & 7;
    const int hnB = wc >> 1;                  // wave's B-half
    const int rB0 = (wc & 1) * 64 + lr;       // local row base within B-half

#define RDA(i, ks) (*(const bf16x8*)&As[p][wr][lr + 16 * (i)][((((ks) * 4 + lg)) ^ xA) * 8])
#define RDB(j, ks) (*(const bf16x8*)&Bs[p][hnB][rB0 + 16 * (j)][((((ks) * 4 + lg)) ^ xB) * 8])
#define MFMA_(d, a_, b_) d = __builtin_amdgcn_mfma_f32_16x16x32_bf16(a_, b_, d, 0, 0, 0)

    // prologue: fully stage K-tiles 0 and 1 (8+8 loads); gate tile 0 (tile 1 flies on)
    STG_A(0, 0); STG_A(0, 1); STG_B(0, 0); STG_B(0, 1);
    STG_A(1, 0); STG_A(1, 1); STG_B(1, 0); STG_B(1, 1);
    asm volatile("s_waitcnt vmcnt(8)" ::: "memory");
    asm volatile("s_barrier" ::: "memory");

    for (int kt = 0; kt < NKTH; ++kt) {
        const int p = kt & 1;
        const bool pf = (kt + 2 < NKTH);
        bf16x8 a0[4][2], a1[4][2], b0[2][2], b1[2][2];

        // ---- phase 0: read a0 + b0 | MFMA quadrant (m0-3 x n0-1) ----
#pragma unroll
        for (int i = 0; i < 4; ++i) { a0[i][0] = RDA(i, 0); a0[i][1] = RDA(i, 1); }
#pragma unroll
        for (int j = 0; j < 2; ++j) { b0[j][0] = RDB(j, 0); b0[j][1] = RDB(j, 1); }
        asm volatile("s_barrier" ::: "memory");
        __builtin_amdgcn_s_setprio(1);
#pragma unroll
        for (int i = 0; i < 4; ++i)
#pragma unroll
            for (int j = 0; j < 2; ++j) {
                MFMA_(acc[i][j], a0[i][0], b0[j][0]);
                MFMA_(acc[i][j], a0[i][1], b0[j][1]);
            }
        __builtin_amdgcn_s_setprio(0);
        asm volatile("s_barrier" ::: "memory");

        // ---- phase 1: read b1 | MFMA quadrant (m0-3 x n2-3) ----
#pragma unroll
        for (int j = 0; j < 2; ++j) { b1[j][0] = RDB(j + 2, 0); b1[j][1] = RDB(j + 2, 1); }
        asm volatile("s_barrier" ::: "memory");
        __builtin_amdgcn_s_setprio(1);
#pragma unroll
        for (int i = 0; i < 4; ++i)
#pragma unroll
            for (int j = 0; j < 2; ++j) {
                MFMA_(acc[i][j + 2], a0[i][0], b1[j][0]);
                MFMA_(acc[i][j + 2], a0[i][1], b1[j][1]);
            }
        __builtin_amdgcn_s_setprio(0);
        asm volatile("s_barrier" ::: "memory");

        // ---- phase 2: read a1 | stage B halves of kt+2 | MFMA quadrant (m4-7 x n2-3) ----
#pragma unroll
        for (int i = 0; i < 4; ++i) { a1[i][0] = RDA(i + 4, 0); a1[i][1] = RDA(i + 4, 1); }
        if (pf) { STG_B(kt + 2, 0); STG_B(kt + 2, 1); }
        asm volatile("s_barrier" ::: "memory");
        __builtin_amdgcn_s_setprio(1);
#pragma unroll
        for (int i = 0; i < 4; ++i)
#pragma unroll
            for (int j = 0; j < 2; ++j) {
                MFMA_(acc[i + 4][j + 2], a1[i][0], b1[j][0]);
                MFMA_(acc[i + 4][j + 2], a1[i][1], b1[j][1]);
            }
        __builtin_amdgcn_s_setprio(0);
        asm volatile("s_barrier" ::: "memory");

        // ---- phase 3: stage A halves of kt+2 | counted gate for kt+1 | MFMA (m4-7 x n0-1) ----
        if (pf) {
            STG_A(kt + 2, 0); STG_A(kt + 2, 1);
            asm volatile("s_waitcnt vmcnt(8)" ::: "memory");   // kt+1 landed; kt+2's 8 fly on
        } else if (kt + 1 < NKTH) {
            asm volatile("s_waitcnt vmcnt(0)" ::: "memory");   // tail: drain for last tile
        }
        asm volatile("s_barrier" ::: "memory");
        __builtin_amdgcn_s_setprio(1);
#pragma unroll
        for (int i = 0; i < 4; ++i)
#pragma unroll
            for (int j = 0; j < 2; ++j) {
                MFMA_(acc[i + 4][j], a1[i][0], b0[j][0]);
                MFMA_(acc[i + 4][j], a1[i][1], b0[j][1]);
            }
        __builtin_amdgcn_s_setprio(0);
        asm volatile("s_barrier" ::: "memory");
    }

    // epilogue: pack row-pairs (rows 2r, 2r+1) as 2xbf16 in one uint; stream (no atomics).
    // C/D map: col=lane&15, row=(lane>>4)*4+reg -> row0 even, rg pairs {0,1},{2,3}.
    unsigned* pout = parts + (size_t)ksp * (BATCH / 2) * OUT_F;
    const int col  = bn0 + wc * 64 + lr;
    const int row0 = bm0 + wr * 128 + lg * 4;
#pragma unroll
    for (int i = 0; i < 8; ++i) {
        const int rp = (row0 + i * 16) >> 1;    // row-pair index
#pragma unroll
        for (int j = 0; j < 4; ++j) {
            unsigned u0 = bf16_bits(acc[i][j][0]) | (bf16_bits(acc[i][j][1]) << 16);
            unsigned u1 = bf16_bits(acc[i][j][2]) | (bf16_bits(acc[i][j][3]) << 16);
            pout[(size_t)rp * OUT_F + col + j * 16]       = u0;
            pout[(size_t)(rp + 1) * OUT_F + col + j * 16] = u1;
        }
    }
#undef STG_A
#undef STG_B
#undef RDA
#undef RDB
#undef MFMA_
}

// ---------------- 4) reduce bf16-packed partials + bias -> out (R14-exact) ----------------
__global__ void reduce_bias_kernel(const unsigned* __restrict__ parts,
                                   const float* __restrict__ bias,
                                   float* __restrict__ out) {
    const int NPQ = (BATCH / 2) * (OUT_F / 4);        // uint4 elements per slice
    int i = blockIdx.x * blockDim.x + threadIdx.x;
    if (i >= NPQ) return;
    float se[4] = {0.f, 0.f, 0.f, 0.f};               // even row (2rp)
    float so[4] = {0.f, 0.f, 0.f, 0.f};               // odd row (2rp+1)
#pragma unroll
    for (int k = 0; k < KSPLIT; ++k) {
        uint4 v = ((const uint4*)parts)[(size_t)k * NPQ + i];
        se[0] += bf16_val(v.x & 0xFFFFu); so[0] += bf16_val(v.x >> 16);
        se[1] += bf16_val(v.y & 0xFFFFu); so[1] += bf16_val(v.y >> 16);
        se[2] += bf16_val(v.z & 0xFFFFu); so[2] += bf16_val(v.z >> 16);
        se[3] += bf16_val(v.w & 0xFFFFu); so[3] += bf16_val(v.w >> 16);
    }
    const int cq = i & (OUT_F / 4 - 1);               // col/4
    const int rp = i / (OUT_F / 4);                   // row pair
    float4 bv = ((const float4*)bias)[cq];
    float4 oe = make_float4(se[0] + bv.x, se[1] + bv.y, se[2] + bv.z, se[3] + bv.w);
    float4 oo = make_float4(so[0] + bv.x, so[1] + bv.y, so[2] + bv.z, so[3] + bv.w);
    ((float4*)out)[(size_t)(2 * rp) * (OUT_F / 4) + cq]     = oe;
    ((float4*)out)[(size_t)(2 * rp + 1) * (OUT_F / 4) + cq] = oo;
}

extern "C" void kernel_launch(void* const* d_in, const int* in_sizes, int n_in,
                              void* d_out, int out_size, void* d_ws, size_t ws_size,
                              hipStream_t stream) {
    const float* x    = (const float*)d_in[0];   // (512, 4096) f32
    const float* wv   = (const float*)d_in[1];   // (nnz,) f32
    const float* bias = (const float*)d_in[2];   // (4096,) f32
    const int*   idx  = (const int*)d_in[3];     // (2, nnz) int32: rows then cols
    const int nnz = in_sizes[1];
    const int* rows = idx;
    const int* cols = idx + nnz;
    float* out = (float*)d_out;

    // workspace layout (16 B aligned chunks)
    char* ws = (char*)d_ws;
    __hip_bfloat16* Wb = (__hip_bfloat16*)ws; ws += (size_t)OUT_F * IN_F * sizeof(__hip_bfloat16); // 32 MB
    __hip_bfloat16* xb = (__hip_bfloat16*)ws; ws += (size_t)BATCH * IN_F * sizeof(__hip_bfloat16); // 4 MB
    int* counts = (int*)ws;                   ws += (size_t)OUT_F * CSTR * sizeof(int);            // 256 KB
    unsigned* pairs = (unsigned*)ws;          ws += (size_t)OUT_F * CAP * sizeof(unsigned) + 256;  // ~3.4 MB
    unsigned* parts = (unsigned*)ws;          // KSPLIT * (BATCH/2) * OUT_F * 4 B = 32 MB

    // 0) x->bf16 + counts<-0
    const int NTOT = BATCH * IN_F / 4 + OUT_F;
    convert_cnt_kernel<<<(NTOT + 255) / 256, 256, 0, stream>>>(x, xb, counts);

    // 1) bucket entries by row (packed 4 B: bf16 weight | col); padded counters
    int nthreads = (nnz + 3) / 4;
    int nb = (nthreads + 255) / 256;
    scatter_pairs_kernel<<<nb, 256, 0, stream>>>(rows, cols, wv, nnz, counts, pairs);

    // 2) densify W (sums duplicates via LDS atomics; writes zeros everywhere else)
    densify_rows_kernel<<<OUT_F, 256, 0, stream>>>(pairs, counts, Wb);

    // 3) dense MFMA GEMM, 256^2 tile, K-split=8, 4-double-barrier-phase + counted gate
    gemm_part_kernel<<<NWG, 512, 0, stream>>>(xb, Wb, parts);

    // 4) sum partials + bias -> out
    const int NPQ = (BATCH / 2) * (OUT_F / 4);
    reduce_bias_kernel<<<(NPQ + 255) / 256, 256, 0, stream>>>(parts, bias, out);
}

// Round 20
// 66.192 us; speedup vs baseline: 1.0719x; 1.0719x over previous
//
#include <hip/hip_runtime.h>
#include <hip/hip_bf16.h>

#define BATCH  512
#define IN_F   4096
#define OUT_F  4096

typedef __attribute__((ext_vector_type(8))) short bf16x8;   // 8 bf16 = 4 VGPR (MFMA A/B frag)
typedef __attribute__((ext_vector_type(4))) float f32x4;    // MFMA C/D frag

// bf16 round-to-nearest-even bits from fp32
__device__ __forceinline__ unsigned bf16_bits(float f) {
    unsigned u = __float_as_uint(f);
    return (u + 0x7FFFu + ((u >> 16) & 1u)) >> 16;
}
__device__ __forceinline__ float bf16_val(unsigned bits16) {
    return __uint_as_float(bits16 << 16);
}

// ---------------- 0) convert x fp32 -> bf16  +  zero dense W ----------------
__global__ void convert_zero_kernel(const float* __restrict__ x, __hip_bfloat16* __restrict__ xb,
                                    float4* __restrict__ wz) {
    const int NC = BATCH * IN_F / 4;          // 524288 x-convert units (float4 each)
    const int NW = OUT_F * IN_F * 2 / 16;     // 2097152 float4 zero-stores (32 MB)
    int i = blockIdx.x * blockDim.x + threadIdx.x;
    if (i < NC) {
        float4 v = ((const float4*)x)[i];
        unsigned lo = bf16_bits(v.x) | (bf16_bits(v.y) << 16);
        unsigned hi = bf16_bits(v.z) | (bf16_bits(v.w) << 16);
        ((uint2*)xb)[i] = make_uint2(lo, hi);
    } else if (i < NC + NW) {
        wz[i - NC] = make_float4(0.f, 0.f, 0.f, 0.f);
    }
}

// ---------------- 1) scatter: bf16 atomic-add (CAS) directly into dense W ----------------
// Duplicate coords (~1.5% of entries) sum via the CAS loop; contention ~0 so the loop
// runs once almost always. Device-scope CAS -> coherent across XCDs.
__device__ __forceinline__ void add_bf16(unsigned* __restrict__ Wb32, int r, int c, float val) {
    unsigned* addr = &Wb32[((size_t)r * IN_F + c) >> 1];
    const bool hi = c & 1;
    unsigned old = *addr, assumed;
    do {
        assumed = old;
        unsigned cur = hi ? (assumed >> 16) : (assumed & 0xFFFFu);
        unsigned nb  = bf16_bits(bf16_val(cur) + val);
        unsigned next = hi ? ((nb << 16) | (assumed & 0xFFFFu))
                           : ((assumed & 0xFFFF0000u) | nb);
        old = atomicCAS(addr, assumed, next);
    } while (old != assumed);
}

__global__ void scatter_cas_kernel(const int* __restrict__ rows,
                                   const int* __restrict__ cols,
                                   const float* __restrict__ w,
                                   int nnz,
                                   unsigned* __restrict__ Wb32) {
    int i = blockIdx.x * blockDim.x + threadIdx.x;
    int i4 = i * 4;
    if (i4 + 4 <= nnz) {
        int4   r  = ((const int4*)rows)[i];
        int4   c  = ((const int4*)cols)[i];
        float4 wv = ((const float4*)w)[i];
        add_bf16(Wb32, r.x, c.x, wv.x);
        add_bf16(Wb32, r.y, c.y, wv.y);
        add_bf16(Wb32, r.z, c.z, wv.z);
        add_bf16(Wb32, r.w, c.w, wv.w);
    } else {
        for (int j = i4; j < nnz; ++j)
            add_bf16(Wb32, rows[j], cols[j], w[j]);
    }
}

// ---------------- 2) GEMM: part[ksp] = x_bf16 @ W^T (slice) -- R14-byte-exact ----------------
// 256^2 tile, BK=64, 8 waves 2Mx4N, counted vmcnt(8), pre-swizzled row-major LDS
// (coalesced staging + 0 bank conflicts, measured). XCD-paired mapping; bf16-packed
// partial streams (no atomics).
#define BM  256
#define BN  256
#define BKT 64
#define KSPLIT 8
#define KH   (IN_F / KSPLIT)            // 512
#define NKTH (KH / BKT)                 // 8
#define NWG  ((BATCH / BM) * (OUT_F / BN) * KSPLIT)   // 256

__global__ __launch_bounds__(512, 1) void gemm_part_kernel(
    const __hip_bfloat16* __restrict__ xb,   // (512, 4096) row-major
    const __hip_bfloat16* __restrict__ Wb,   // (4096, 4096) = (N, K) row-major
    unsigned* __restrict__ parts) {          // KSPLIT x (256, 4096) uint (2 bf16 rows each)

    __shared__ __align__(16) __hip_bfloat16 As[2][BM][BKT];   // 64 KB
    __shared__ __align__(16) __hip_bfloat16 Bs[2][BN][BKT];   // 64 KB

    // XCD-paired decomposition (xcd heuristic: bid % 8)
    const int xcd = blockIdx.x & 7;
    const int r   = blockIdx.x >> 3;          // 0..31
    const int bn0 = (2 * xcd + (r & 1)) * BN; // n tile 0..15
    const int bm0 = ((r >> 1) & 1) * BM;      // m tile 0..1
    const int ksp = r >> 2;                   // 0..7
    const size_t k0 = (size_t)ksp * KH;

    const int t  = threadIdx.x;               // 0..511
    const int l  = t & 63;
    const int w  = t >> 6;                    // wave 0..7
    const int wr = w >> 2;                    // M-half 0..1 (128 rows)
    const int wc = w & 3;                     // N-quarter 0..3 (64 cols)
    const int lr = l & 15;                    // frag lane
    const int lg = l >> 4;                    // k-group 0..3

    f32x4 acc[8][4] = {};

#define STAGE(p, kt) do {                                                                         \
    _Pragma("unroll")                                                                             \
    for (int j = 0; j < 4; ++j) {                                                                 \
        int q = t + j * 512; int row = q >> 3; int kcg = (q & 7) ^ (row & 7);                     \
        __builtin_amdgcn_global_load_lds(                                                         \
            (const unsigned*)(xb + (size_t)(bm0 + row) * IN_F + k0 + (kt) * BKT + kcg * 8),       \
            (unsigned*)((__hip_bfloat16*)As[p] + q * 8), 16, 0, 0);                               \
    }                                                                                             \
    _Pragma("unroll")                                                                             \
    for (int j = 0; j < 4; ++j) {                                                                 \
        int q = t + j * 512; int row = q >> 3; int kcg = (q & 7) ^ (row & 7);                     \
        __builtin_amdgcn_global_load_lds(                                                         \
            (const unsigned*)(Wb + (size_t)(bn0 + row) * IN_F + k0 + (kt) * BKT + kcg * 8),       \
            (unsigned*)((__hip_bfloat16*)Bs[p] + q * 8), 16, 0, 0);                               \
    }                                                                                             \
} while (0)

    const int rowA0 = wr * 128 + lr;          // +16i ; (row&7) == (lr&7) for all i
    const int rowB0 = wc * 64 + lr;
    const int xA = lr & 7;
    const int xB = lr & 7;

    STAGE(0, 0);
    for (int kt = 0; kt < NKTH; ++kt) {
        const int p = kt & 1;
        if (kt + 1 < NKTH) {
            STAGE(p ^ 1, kt + 1);                              // 8 more loads in flight
            asm volatile("s_waitcnt vmcnt(8)" ::: "memory");   // tile kt's 8 landed
        } else {
            asm volatile("s_waitcnt vmcnt(0)" ::: "memory");   // final tile: full drain
        }
        __builtin_amdgcn_s_barrier();                          // all waves: tile kt ready

#pragma unroll
        for (int ks = 0; ks < 2; ++ks) {
            const int kc = ks * 4 + lg;
            bf16x8 a[8], b[4];
#pragma unroll
            for (int i = 0; i < 8; ++i)
                a[i] = *(const bf16x8*)&As[p][rowA0 + 16 * i][(kc ^ xA) * 8];
#pragma unroll
            for (int i = 0; i < 4; ++i)
                b[i] = *(const bf16x8*)&Bs[p][rowB0 + 16 * i][(kc ^ xB) * 8];
#pragma unroll
            for (int i = 0; i < 8; ++i)
#pragma unroll
                for (int j = 0; j < 4; ++j)
                    acc[i][j] = __builtin_amdgcn_mfma_f32_16x16x32_bf16(a[i], b[j], acc[i][j], 0, 0, 0);
        }
        __builtin_amdgcn_s_barrier();   // all waves done reading buf p before restage
    }

    // epilogue: pack row-pairs (rows 2r, 2r+1) as 2xbf16 in one uint; stream (no atomics).
    // C/D map: col=lane&15, row=(lane>>4)*4+reg -> row0 even, rg pairs {0,1},{2,3}.
    unsigned* pout = parts + (size_t)ksp * (BATCH / 2) * OUT_F;
    const int col  = bn0 + wc * 64 + lr;
    const int row0 = bm0 + wr * 128 + lg * 4;
#pragma unroll
    for (int i = 0; i < 8; ++i) {
        const int rp = (row0 + i * 16) >> 1;    // row-pair index
#pragma unroll
        for (int j = 0; j < 4; ++j) {
            unsigned u0 = bf16_bits(acc[i][j][0]) | (bf16_bits(acc[i][j][1]) << 16);
            unsigned u1 = bf16_bits(acc[i][j][2]) | (bf16_bits(acc[i][j][3]) << 16);
            pout[(size_t)rp * OUT_F + col + j * 16]       = u0;
            pout[(size_t)(rp + 1) * OUT_F + col + j * 16] = u1;
        }
    }
#undef STAGE
}

// ---------------- 3) reduce bf16-packed partials + bias -> out (R14-byte-exact) ----------------
__global__ void reduce_bias_kernel(const unsigned* __restrict__ parts,
                                   const float* __restrict__ bias,
                                   float* __restrict__ out) {
    const int NPQ = (BATCH / 2) * (OUT_F / 4);        // uint4 elements per slice
    int i = blockIdx.x * blockDim.x + threadIdx.x;
    if (i >= NPQ) return;
    float se[4] = {0.f, 0.f, 0.f, 0.f};               // even row (2rp)
    float so[4] = {0.f, 0.f, 0.f, 0.f};               // odd row (2rp+1)
#pragma unroll
    for (int k = 0; k < KSPLIT; ++k) {
        uint4 v = ((const uint4*)parts)[(size_t)k * NPQ + i];
        se[0] += bf16_val(v.x & 0xFFFFu); so[0] += bf16_val(v.x >> 16);
        se[1] += bf16_val(v.y & 0xFFFFu); so[1] += bf16_val(v.y >> 16);
        se[2] += bf16_val(v.z & 0xFFFFu); so[2] += bf16_val(v.z >> 16);
        se[3] += bf16_val(v.w & 0xFFFFu); so[3] += bf16_val(v.w >> 16);
    }
    const int cq = i & (OUT_F / 4 - 1);               // col/4
    const int rp = i / (OUT_F / 4);                   // row pair
    float4 bv = ((const float4*)bias)[cq];
    float4 oe = make_float4(se[0] + bv.x, se[1] + bv.y, se[2] + bv.z, se[3] + bv.w);
    float4 oo = make_float4(so[0] + bv.x, so[1] + bv.y, so[2] + bv.z, so[3] + bv.w);
    ((float4*)out)[(size_t)(2 * rp) * (OUT_F / 4) + cq]     = oe;
    ((float4*)out)[(size_t)(2 * rp + 1) * (OUT_F / 4) + cq] = oo;
}

extern "C" void kernel_launch(void* const* d_in, const int* in_sizes, int n_in,
                              void* d_out, int out_size, void* d_ws, size_t ws_size,
                              hipStream_t stream) {
    const float* x    = (const float*)d_in[0];   // (512, 4096) f32
    const float* wv   = (const float*)d_in[1];   // (nnz,) f32
    const float* bias = (const float*)d_in[2];   // (4096,) f32
    const int*   idx  = (const int*)d_in[3];     // (2, nnz) int32: rows then cols
    const int nnz = in_sizes[1];
    const int* rows = idx;
    const int* cols = idx + nnz;
    float* out = (float*)d_out;

    // workspace layout (16 B aligned chunks)
    char* ws = (char*)d_ws;
    __hip_bfloat16* Wb = (__hip_bfloat16*)ws; ws += (size_t)OUT_F * IN_F * sizeof(__hip_bfloat16); // 32 MB
    __hip_bfloat16* xb = (__hip_bfloat16*)ws; ws += (size_t)BATCH * IN_F * sizeof(__hip_bfloat16); // 4 MB
    unsigned* parts = (unsigned*)ws;          // KSPLIT * (BATCH/2) * OUT_F * 4 B = 32 MB

    // 0) x->bf16 + Wb<-0 (fused streaming pass)
    const int NTOT = BATCH * IN_F / 4 + OUT_F * IN_F * 2 / 16;
    convert_zero_kernel<<<(NTOT + 255) / 256, 256, 0, stream>>>(x, xb, (float4*)Wb);

    // 1) scatter entries directly into dense bf16 W (CAS add; duplicates summed)
    int nthreads = (nnz + 3) / 4;
    int nb = (nthreads + 255) / 256;
    scatter_cas_kernel<<<nb, 256, 0, stream>>>(rows, cols, wv, nnz, (unsigned*)Wb);

    // 2) dense MFMA GEMM, 256^2 tile, K-split=8, bf16 partial streams (R14-exact)
    gemm_part_kernel<<<NWG, 512, 0, stream>>>(xb, Wb, parts);

    // 3) sum partials + bias -> out (R14-exact)
    const int NPQ = (BATCH / 2) * (OUT_F / 4);
    reduce_bias_kernel<<<(NPQ + 255) / 256, 256, 0, stream>>>(parts, bias, out);
}